// Round 7
// baseline (195.613 us; speedup 1.0000x reference)
//
#include <hip/hip_runtime.h>

constexpr int BATCH = 32;
constexpr int HH = 256, WW = 256;
constexpr int NPIX = HH * WW;
constexpr int STEPS = 15;
constexpr float R_C = 3.9f, EPS_C = 0.3f, BETA_C = 0.15f;
constexpr float CLAMP_LO = 1e-4f, CLAMP_HI = 1.0f - 1e-4f;

typedef __attribute__((ext_vector_type(8))) short short8;
typedef __attribute__((ext_vector_type(4))) float f32x4;

__device__ inline unsigned short f2bf(float f) {
  unsigned int u = __float_as_uint(f);
  return (unsigned short)((u + 0x7fffu + ((u >> 16) & 1u)) >> 16);
}

// Virtual-tap tables (conv): 18 real taps (9 d1 + 9 d2) + 2 zero pads,
// permuted for LDS bank phase diversity.
__constant__ int VT_OY[20] = {1,2,3,1, 3,0,0,2, 0,2,2,4, 4,4,3,2, 0,0,2,1};
__constant__ int VT_OX[20] = {3,2,3,1, 1,4,2,4, 0,2,0,2, 4,0,2,1, 1,3,3,2};
__constant__ int VT_SRC[20]= {0,0,0,0, 0,1,1,1, 1,1,1,1, 1,1,0,0, 2,2,0,0};
__constant__ int VT_TAP[20]= {2,4,8,0, 6,2,1,5, 0,4,3,7, 8,6,7,3, 0,0,5,1};

// ------------------------------------------------------------------ prep
__global__ void prep_kernel(const float* __restrict__ Wp1,
                            const float* __restrict__ Wp2,
                            const float* __restrict__ bp1,
                            const float* __restrict__ bp2,
                            const float* __restrict__ alpha,
                            const float* __restrict__ Wu1,
                            unsigned short* __restrict__ apack,
                            unsigned short* __restrict__ u1pack,
                            float* __restrict__ bfu) {
  int i = blockIdx.x * 256 + threadIdx.x;
  if (i < 5120) {
    int j = i & 7, lane = (i >> 3) & 63, tm = i >> 9;
    int mt = tm & 1;
    int o = (lane & 15) + 16 * mt, g = lane >> 4, vt = (tm >> 1) * 4 + g;
    float w = 0.f;
    if (j < 6 && VT_SRC[vt] != 2) {
      int base = o * 54 + j * 9 + VT_TAP[vt];
      w = (VT_SRC[vt] == 0) ? Wp1[base] : Wp2[base] * alpha[o];
    }
    apack[i] = f2bf(w);
  } else if (i < 6144) {
    int i2 = i - 5120;
    int j = i2 & 7, lane = (i2 >> 3) & 63, mt = i2 >> 9;
    int o = (lane & 15) + 16 * mt, g = lane >> 4;
    u1pack[i2] = f2bf(Wu1[o * 32 + 8 * g + j]);
  } else if (i < 6176) {
    int o = i - 6144;
    bfu[o] = bp1[o] + bp2[o] * alpha[o];
  }
}

// --------------------------------------------- stencil + online attention
// Band: block owns 256-wide x 16 output rows; region rows 0..45 (padded to
// 48), gy0 = band*16-15, tile rows = region rows 15..30 (= V_15 of the
// shrinking cone V_s = [s, 45-s]; update range at step s = [s+1, 44-s]).
// 12 waves; wave = 4-row x 256-wide strip; g/x/accum in VGPRs.
// LDS: SINGLE full-row `mapped` buffer 48 x 264 words (4 pad cols each
// side, zeroed once = exact horizontal zero-padding; 49.5 KB -> 2 blocks/CU
// resident, 24 waves).  Two barriers per step (R3-proven structure):
// [bar] write own 4 rows [bar] read halo rows + side scalars, update, exp.
// NO shuffles, NO slim buffers: R5/R6 used shuffle side-halos + boundary-
// row-only LDS and both failed bit-identically (absmax 0.59) while this
// component set matches the passing R3/R4 kernels.
constexpr int BANDH = 16;
constexpr int LSTR2 = 264;  // [4 pad][256][4 pad] words
constexpr int TS = 768;

__global__ __launch_bounds__(TS, 6) void stencil_kernel(
    const float* __restrict__ x, const float* __restrict__ Kl,
    const float* __restrict__ Wq, const float* __restrict__ bq,
    const float* __restrict__ Wk, float* __restrict__ lastO,
    float* __restrict__ sO) {
  __shared__ float buf[48 * LSTR2];  // 50688 B

  const int band = blockIdx.x, b = blockIdx.y;
  const int gy0 = band * BANDH - 15;
  const int t = threadIdx.x;
  const int sx = t & 63, sy = t >> 6;  // wave id == strip-row
  const int c0 = 4 * sx, r0 = 4 * sy;
  const float* xim = x + (size_t)b * NPIX;

  // zero pad columns once (48 rows x 8 pad words); fenced by first barrier
  if (t < 384) {
    int r = t >> 3, pw = t & 7;
    buf[r * LSTR2 + (pw < 4 ? pw : 256 + pw)] = 0.f;
  }

  const float k00 = Kl[0], k01 = Kl[1], k02 = Kl[2];
  const float k10 = Kl[3], k11 = Kl[4], k12 = Kl[5];
  const float k20 = Kl[6], k21 = Kl[7], k22 = Kl[8];

  const float swk = Wq[0] * Wk[0] + Wq[1] * Wk[1] + Wq[2] * Wk[2];
  const float sbk = bq[0] * Wk[0] + bq[1] * Wk[1] + bq[2] * Wk[2];
  const float rs3 = 0.57735026918962576f;
  const float a1 = swk * rs3, a0c = sbk * rs3;  // score = (a1*x + a0c)*g

  const int img_lo = (gy0 < 0) ? -gy0 : 0;
  const int img_hi = (255 - gy0 < 45) ? (255 - gy0) : 45;

  float xv[4][4], g[4][4], se[4][4], ws[4][4];
#pragma unroll
  for (int rr = 0; rr < 4; rr++) {
    int ry = r0 + rr, gy = gy0 + ry;
    bool rin = (ry >= img_lo) && (ry <= img_hi);
    f32x4 v = {0.f, 0.f, 0.f, 0.f};
    if (rin) v = *(const f32x4*)&xim[gy * WW + c0];
#pragma unroll
    for (int c = 0; c < 4; c++) {
      xv[rr][c] = v[c];
      g[rr][c] = v[c];
      se[rr][c] = 0.f;
      ws[rr][c] = 0.f;
    }
  }

  // halo row indices (sy==0 top / sy==11 bottom values are dummies: the
  // rows needing them are never inside the update range)
  const int rt = (sy == 0) ? 0 : r0 - 1;
  const int rb = (sy == 11) ? 47 : r0 + 4;

  for (int s = 0; s < STEPS; s++) {
    if (s) __syncthreads();  // fence prior step's reads before overwrite
    // mapped for own rows -> registers + full-row LDS write
    float m[4][4];
#pragma unroll
    for (int rr = 0; rr < 4; rr++) {
      f32x4 mv;
#pragma unroll
      for (int c = 0; c < 4; c++) {
        m[rr][c] = R_C * g[rr][c] * (1.f - g[rr][c]);
        mv[c] = m[rr][c];
      }
      *(f32x4*)&buf[(r0 + rr) * LSTR2 + 4 + c0] = mv;
    }
    __syncthreads();

    // halo rows via b128 + side/corner scalars from pad-col layout
    f32x4 T4 = *(const f32x4*)&buf[rt * LSTR2 + 4 + c0];
    float TL = buf[rt * LSTR2 + 3 + c0];
    float TR = buf[rt * LSTR2 + 8 + c0];
    f32x4 B4 = *(const f32x4*)&buf[rb * LSTR2 + 4 + c0];
    float BL = buf[rb * LSTR2 + 3 + c0];
    float BR = buf[rb * LSTR2 + 8 + c0];
    float sl[4], sr[4];
#pragma unroll
    for (int rr = 0; rr < 4; rr++) {
      sl[rr] = buf[(r0 + rr) * LSTR2 + 3 + c0];
      sr[rr] = buf[(r0 + rr) * LSTR2 + 8 + c0];
    }

    float W[6][6];
    W[0][0] = TL; W[0][1] = T4[0]; W[0][2] = T4[1];
    W[0][3] = T4[2]; W[0][4] = T4[3]; W[0][5] = TR;
#pragma unroll
    for (int rr = 0; rr < 4; rr++) {
      W[1 + rr][0] = sl[rr];
#pragma unroll
      for (int c = 0; c < 4; c++) W[1 + rr][1 + c] = m[rr][c];
      W[1 + rr][5] = sr[rr];
    }
    W[5][0] = BL; W[5][1] = B4[0]; W[5][2] = B4[1];
    W[5][3] = B4[2]; W[5][4] = B4[3]; W[5][5] = BR;

    const int ulo = (s + 1 > img_lo) ? s + 1 : img_lo;
    const int uhi = (44 - s < img_hi) ? 44 - s : img_hi;

#pragma unroll
    for (int rr = 0; rr < 4; rr++) {
      const int ry = r0 + rr;
      if (ry >= ulo && ry <= uhi) {  // wave-uniform branch
#pragma unroll
        for (int c = 0; c < 4; c++) {
          float mc = W[rr + 1][c + 1];
          float loc = k00 * W[rr][c] + k01 * W[rr][c + 1] +
                      k02 * W[rr][c + 2] + k10 * W[rr + 1][c] + k11 * mc +
                      k12 * W[rr + 1][c + 2] + k20 * W[rr + 2][c] +
                      k21 * W[rr + 2][c + 1] + k22 * W[rr + 2][c + 2];
          float ph = (1.f - EPS_C) * mc + EPS_C * loc;
          float gn = (1.f - BETA_C) * ph + BETA_C * xv[rr][c];
          g[rr][c] = fminf(fmaxf(gn, CLAMP_LO), CLAMP_HI);
        }
      }
      if (ry >= 15 && ry <= 30) {  // wave-uniform: tile rows only
#pragma unroll
        for (int c = 0; c < 4; c++) {
          float gv = g[rr][c];
          float e = __expf((a1 * xv[rr][c] + a0c) * gv);
          se[rr][c] += e;
          ws[rr][c] = fmaf(e, gv, ws[rr][c]);
        }
      }
    }
  }

#pragma unroll
  for (int rr = 0; rr < 4; rr++) {
    const int ry = r0 + rr;
    if (ry >= 15 && ry <= 30) {
      int gy = gy0 + ry;
      size_t gi = (size_t)b * NPIX + (size_t)gy * WW + c0;
      f32x4 gv, sv;
#pragma unroll
      for (int c = 0; c < 4; c++) {
        gv[c] = g[rr][c];
        sv[c] = ws[rr][c] / se[rr][c];
      }
      *(f32x4*)&lastO[gi] = gv;
      *(f32x4*)&sO[gi] = sv;
    }
  }
}

// ------------------------------------------------- conv stack via MFMA
constexpr int CT = 32;
constexpr int NR = 36, NCS = 37;
constexpr int T2 = 256;

__global__ __launch_bounds__(T2) void conv_kernel(
    const float* __restrict__ x, const float* __restrict__ lastA,
    const float* __restrict__ sA, const float* __restrict__ Wv,
    const float* __restrict__ bv, const unsigned short* __restrict__ apackG,
    const unsigned short* __restrict__ u1packG,
    const float* __restrict__ bfuG, const float* __restrict__ bu1G,
    const float* __restrict__ Wu2G, const float* __restrict__ bu2G,
    float* __restrict__ outp) {
  __shared__ __align__(16) unsigned short ncaL[NR * NCS * 8];
  __shared__ __align__(16) unsigned short featL[4 * 16 * 40];
  __shared__ __align__(16) float outL[CT * CT];

  const int cx0 = blockIdx.x * CT, cy0 = blockIdx.y * CT, b = blockIdx.z;
  const int t = threadIdx.x;
  const int w = t >> 6, lane = t & 63;
  const int g = lane >> 4, col = lane & 15;

  const float wv0 = Wv[0], wv1 = Wv[1], wv2 = Wv[2];
  const float bv0 = bv[0], bv1 = bv[1], bv2 = bv[2];
  for (int i = t; i < NR * NR; i += T2) {
    int ry = i / NR, rx = i - ry * NR;
    int gy = cy0 - 2 + ry, gx = cx0 - 2 + rx;
    unsigned short c[8];
    if (gy >= 0 && gy < HH && gx >= 0 && gx < WW) {
      size_t gi = (size_t)b * NPIX + (size_t)gy * WW + gx;
      float xvv = x[gi], lv = lastA[gi], sv = sA[gi];
      c[0] = f2bf(xvv);
      c[1] = f2bf(lv);
      c[2] = f2bf(lv - xvv);
      c[3] = f2bf(wv0 * sv + bv0);
      c[4] = f2bf(wv1 * sv + bv1);
      c[5] = f2bf(wv2 * sv + bv2);
    } else {
      c[0] = c[1] = c[2] = c[3] = c[4] = c[5] = 0;
    }
    short8 v;
    v[0] = (short)c[0]; v[1] = (short)c[1]; v[2] = (short)c[2];
    v[3] = (short)c[3]; v[4] = (short)c[4]; v[5] = (short)c[5];
    v[6] = 0; v[7] = 0;
    *(short8*)&ncaL[(ry * NCS + rx) * 8] = v;
  }

  const short8* ap = (const short8*)apackG;
  short8 wfr[10];
#pragma unroll
  for (int q = 0; q < 10; q++) wfr[q] = ap[q * 64 + lane];
  const short8* up = (const short8*)u1packG;
  short8 u1fr[2];
  u1fr[0] = up[lane];
  u1fr[1] = up[64 + lane];

  float bf0[4], bf1[4], bu1a[4], bu1b[4], wu2a[4], wu2b[4];
#pragma unroll
  for (int r = 0; r < 4; r++) {
    bf0[r] = bfuG[4 * g + r];
    bf1[r] = bfuG[16 + 4 * g + r];
    bu1a[r] = bu1G[4 * g + r];
    bu1b[r] = bu1G[16 + 4 * g + r];
    wu2a[r] = Wu2G[4 * g + r];
    wu2b[r] = Wu2G[16 + 4 * g + r];
  }
  const float bu2v = bu2G[0];

  int bofft[5];
#pragma unroll
  for (int tt = 0; tt < 5; tt++) {
    int vt = 4 * tt + g;
    bofft[tt] = VT_OY[vt] * NCS + VT_OX[vt];
  }

  __syncthreads();

  unsigned short* fw = &featL[w * 640];
  const f32x4 zacc = {0.f, 0.f, 0.f, 0.f};

  for (int rr = 0; rr < 8; rr++) {
    int py = 8 * w + rr;
#pragma unroll
    for (int half = 0; half < 2; half++) {
      int px0 = 16 * half;
      int cbase = py * NCS + px0 + col;
      f32x4 a0 = zacc, a1v = zacc;
#pragma unroll
      for (int tt = 0; tt < 5; tt++) {
        short8 bf = *(const short8*)&ncaL[(cbase + bofft[tt]) * 8];
        a0 = __builtin_amdgcn_mfma_f32_16x16x32_bf16(wfr[2 * tt], bf, a0, 0, 0, 0);
        a1v = __builtin_amdgcn_mfma_f32_16x16x32_bf16(wfr[2 * tt + 1], bf, a1v, 0, 0, 0);
      }
      unsigned p00, p01, p10, p11;
      {
        float f0 = fmaxf(a0[0] + bf0[0], 0.f), f1 = fmaxf(a0[1] + bf0[1], 0.f);
        float f2 = fmaxf(a0[2] + bf0[2], 0.f), f3 = fmaxf(a0[3] + bf0[3], 0.f);
        p00 = (unsigned)f2bf(f0) | ((unsigned)f2bf(f1) << 16);
        p01 = (unsigned)f2bf(f2) | ((unsigned)f2bf(f3) << 16);
        float h0 = fmaxf(a1v[0] + bf1[0], 0.f), h1 = fmaxf(a1v[1] + bf1[1], 0.f);
        float h2 = fmaxf(a1v[2] + bf1[2], 0.f), h3 = fmaxf(a1v[3] + bf1[3], 0.f);
        p10 = (unsigned)f2bf(h0) | ((unsigned)f2bf(h1) << 16);
        p11 = (unsigned)f2bf(h2) | ((unsigned)f2bf(h3) << 16);
      }
      uint2 wv_a; wv_a.x = p00; wv_a.y = p01;
      uint2 wv_b; wv_b.x = p10; wv_b.y = p11;
      *(uint2*)&fw[col * 40 + 4 * g] = wv_a;
      *(uint2*)&fw[col * 40 + 16 + 4 * g] = wv_b;
      short8 pf = *(const short8*)&fw[col * 40 + 8 * g];
      f32x4 hA = __builtin_amdgcn_mfma_f32_16x16x32_bf16(u1fr[0], pf, zacc, 0, 0, 0);
      f32x4 hB = __builtin_amdgcn_mfma_f32_16x16x32_bf16(u1fr[1], pf, zacc, 0, 0, 0);
      float cp = 0.f;
#pragma unroll
      for (int r = 0; r < 4; r++) {
        cp += wu2a[r] * fmaxf(hA[r] + bu1a[r], 0.f);
        cp += wu2b[r] * fmaxf(hB[r] + bu1b[r], 0.f);
      }
      cp += __shfl_xor(cp, 16);
      cp += __shfl_xor(cp, 32);
      float lastv = lastA[(size_t)b * NPIX + (size_t)(cy0 + py) * WW +
                          (cx0 + px0 + col)];
      float ov = fminf(fmaxf(lastv + bu2v + cp, 0.f), 1.f);
      if (lane < 16) outL[py * CT + px0 + col] = ov;
    }
  }

  float4 o4 = *(float4*)&outL[t * 4];
  int row = (t * 4) >> 5, colf = (t * 4) & 31;
  *(float4*)&outp[(size_t)b * NPIX + (size_t)(cy0 + row) * WW + cx0 + colf] = o4;
}

extern "C" void kernel_launch(void* const* d_in, const int* in_sizes, int n_in,
                              void* d_out, int out_size, void* d_ws,
                              size_t ws_size, hipStream_t stream) {
  const float* x = (const float*)d_in[0];
  const float* Kl = (const float*)d_in[1];
  const float* Wq = (const float*)d_in[2];
  const float* bq = (const float*)d_in[3];
  const float* Wk = (const float*)d_in[4];
  // d_in[5] = bk: softmax-invariant, unused
  const float* Wv = (const float*)d_in[6];
  const float* bv = (const float*)d_in[7];
  const float* Wp1 = (const float*)d_in[8];
  const float* bp1 = (const float*)d_in[9];
  const float* Wp2 = (const float*)d_in[10];
  const float* bp2 = (const float*)d_in[11];
  const float* alpha = (const float*)d_in[12];
  const float* Wu1 = (const float*)d_in[13];
  const float* bu1 = (const float*)d_in[14];
  const float* Wu2 = (const float*)d_in[15];
  const float* bu2 = (const float*)d_in[16];
  float* outp = (float*)d_out;

  float* ws = (float*)d_ws;
  float* lastA = ws;
  float* sA = ws + (size_t)BATCH * NPIX;
  unsigned short* apack = (unsigned short*)(ws + 2 * (size_t)BATCH * NPIX);
  unsigned short* u1pack = apack + 5120;
  float* bfu = (float*)(u1pack + 1024);

  prep_kernel<<<25, 256, 0, stream>>>(Wp1, Wp2, bp1, bp2, alpha, Wu1, apack,
                                      u1pack, bfu);

  dim3 g1(HH / BANDH, BATCH);  // 16 x 32 = 512 blocks = 2 per CU
  stencil_kernel<<<g1, TS, 0, stream>>>(x, Kl, Wq, bq, Wk, lastA, sA);

  dim3 g2(WW / CT, HH / CT, BATCH);
  conv_kernel<<<g2, T2, 0, stream>>>(x, lastA, sA, Wv, bv, apack, u1pack, bfu,
                                     bu1, Wu2, bu2, outp);
}

// Round 8
// 129.421 us; speedup vs baseline: 1.5114x; 1.5114x over previous
//
#include <hip/hip_runtime.h>

constexpr int BATCH = 32;
constexpr int HH = 256, WW = 256;
constexpr int NPIX = HH * WW;
constexpr int STEPS = 15;
constexpr float R_C = 3.9f, EPS_C = 0.3f, BETA_C = 0.15f;
constexpr float CLAMP_LO = 1e-4f, CLAMP_HI = 1.0f - 1e-4f;

typedef __attribute__((ext_vector_type(8))) short short8;
typedef __attribute__((ext_vector_type(4))) float f32x4;

__device__ inline unsigned short f2bf(float f) {
  unsigned int u = __float_as_uint(f);
  return (unsigned short)((u + 0x7fffu + ((u >> 16) & 1u)) >> 16);
}

__constant__ int VT_OY[20] = {1,2,3,1, 3,0,0,2, 0,2,2,4, 4,4,3,2, 0,0,2,1};
__constant__ int VT_OX[20] = {3,2,3,1, 1,4,2,4, 0,2,0,2, 4,0,2,1, 1,3,3,2};
__constant__ int VT_SRC[20]= {0,0,0,0, 0,1,1,1, 1,1,1,1, 1,1,0,0, 2,2,0,0};
__constant__ int VT_TAP[20]= {2,4,8,0, 6,2,1,5, 0,4,3,7, 8,6,7,3, 0,0,5,1};

// ------------------------------------------------------------------ prep
__global__ void prep_kernel(const float* __restrict__ Wp1,
                            const float* __restrict__ Wp2,
                            const float* __restrict__ bp1,
                            const float* __restrict__ bp2,
                            const float* __restrict__ alpha,
                            const float* __restrict__ Wu1,
                            unsigned short* __restrict__ apack,
                            unsigned short* __restrict__ u1pack,
                            float* __restrict__ bfu) {
  int i = blockIdx.x * 256 + threadIdx.x;
  if (i < 5120) {
    int j = i & 7, lane = (i >> 3) & 63, tm = i >> 9;
    int mt = tm & 1;
    int o = (lane & 15) + 16 * mt, g = lane >> 4, vt = (tm >> 1) * 4 + g;
    float w = 0.f;
    if (j < 6 && VT_SRC[vt] != 2) {
      int base = o * 54 + j * 9 + VT_TAP[vt];
      w = (VT_SRC[vt] == 0) ? Wp1[base] : Wp2[base] * alpha[o];
    }
    apack[i] = f2bf(w);
  } else if (i < 6144) {
    int i2 = i - 5120;
    int j = i2 & 7, lane = (i2 >> 3) & 63, mt = i2 >> 9;
    int o = (lane & 15) + 16 * mt, g = lane >> 4;
    u1pack[i2] = f2bf(Wu1[o * 32 + 8 * g + j]);
  } else if (i < 6176) {
    int o = i - 6144;
    bfu[o] = bp1[o] + bp2[o] * alpha[o];
  }
}

// ---------------------------------------- 5-step chained stencil launch
// Each launch advances g by 5 steps (halo 5).  Band: 256-wide x 16 output
// rows; region rows 0..25 = global band*16-5 .. band*16+20, tile = region
// rows 5..20 (cone V_s=[s,25-s]; update range [s+1,24-s] ∩ image).  14
// waves x (2 rows x 256 wide); 8 px/thread keeps persistent VGPR state at
// 32 (xv,g,se,ws) + ~38 transient -> fits the 7-wave/SIMD tier (<=73 VGPR,
// launch_bounds(896,7)) with NO scratch spill (R7's 4-row strips at the
// 6-wave bound spilled ~70 regs -> 243MB of HBM scratch traffic).
// 2 blocks/CU resident (28 waves).  LDS: single full-row mapped buffer
// 28 x 264 (pad cols = exact zero padding), 29.6 KB; two barriers/step
// (R7-proven).  Online-softmax se/ws round-trip f32 through d_ws between
// launches (bit-exact: same fmaf sequence).  g ping-pongs (gIn!=gOut).
constexpr int LSTR5 = 264;
constexpr int T5 = 896;

__global__ __launch_bounds__(T5, 7) void stencil5_kernel(
    const float* __restrict__ x, const float* __restrict__ Kl,
    const float* __restrict__ Wq, const float* __restrict__ bq,
    const float* __restrict__ Wk, const float* __restrict__ gIn,
    float* __restrict__ gOut, float* __restrict__ seB,
    float* __restrict__ wsB, float* __restrict__ sAout, int first, int last) {
  __shared__ float buf[28 * LSTR5];  // 29568 B

  const int band = blockIdx.x, b = blockIdx.y;
  const int gy0 = band * 16 - 5;
  const int t = threadIdx.x;
  const int sx = t & 63, sy = t >> 6;  // wave sy owns region rows 2sy, 2sy+1
  const int c0 = 4 * sx, r0 = 2 * sy;
  const float* xim = x + (size_t)b * NPIX;
  const float* gim = (gIn ? gIn : x) + (size_t)b * NPIX;

  // zero the pad columns once (28 rows x 8 words); fenced by first barrier
  if (t < 224) {
    int r = t >> 3, pw = t & 7;
    buf[r * LSTR5 + (pw < 4 ? pw : 256 + pw)] = 0.f;
  }

  const float k00 = Kl[0], k01 = Kl[1], k02 = Kl[2];
  const float k10 = Kl[3], k11 = Kl[4], k12 = Kl[5];
  const float k20 = Kl[6], k21 = Kl[7], k22 = Kl[8];

  const float swk = Wq[0] * Wk[0] + Wq[1] * Wk[1] + Wq[2] * Wk[2];
  const float sbk = bq[0] * Wk[0] + bq[1] * Wk[1] + bq[2] * Wk[2];
  const float rs3 = 0.57735026918962576f;
  const float a1 = swk * rs3, a0c = sbk * rs3;  // score = (a1*x + a0c)*g

  const int img_lo = (gy0 < 0) ? -gy0 : 0;
  const int img_hi = (255 - gy0 < 25) ? (255 - gy0) : 25;

  float xv[2][4], g[2][4], se[2][4], ws[2][4];
#pragma unroll
  for (int rr = 0; rr < 2; rr++) {
    int ry = r0 + rr, gy = gy0 + ry;
    bool rin = (ry >= img_lo) && (ry <= img_hi);
    bool tile = (ry >= 5) && (ry <= 20);
    size_t gi = (size_t)b * NPIX + (size_t)gy * WW + c0;
    f32x4 xvv = {0.f, 0.f, 0.f, 0.f}, gvv = {0.f, 0.f, 0.f, 0.f};
    if (rin) {
      xvv = *(const f32x4*)&xim[(size_t)gy * WW + c0];
      gvv = first ? xvv : *(const f32x4*)&gim[(size_t)gy * WW + c0];
    }
    f32x4 sev = {0.f, 0.f, 0.f, 0.f}, wsv = {0.f, 0.f, 0.f, 0.f};
    if (!first && tile) {
      sev = *(const f32x4*)&seB[gi];
      wsv = *(const f32x4*)&wsB[gi];
    }
#pragma unroll
    for (int c = 0; c < 4; c++) {
      xv[rr][c] = xvv[c];
      g[rr][c] = gvv[c];
      se[rr][c] = sev[c];
      ws[rr][c] = wsv[c];
    }
  }

  // halo rows: top needed only for updating row r0 (never for sy==0: row 0
  // is cone boundary, never updated); bottom = row r0+2 (sy==13's rows
  // 26,27 are pad rows, never updated -> rb=27 only feeds dead lanes)
  const int rt = (sy == 0) ? 0 : r0 - 1;
  const int rb = (sy == 13) ? 27 : r0 + 2;

  for (int s = 0; s < 5; s++) {
    if (s) __syncthreads();  // fence prior step's reads before overwrite
    float m[2][4];
#pragma unroll
    for (int rr = 0; rr < 2; rr++) {
      f32x4 mv;
#pragma unroll
      for (int c = 0; c < 4; c++) {
        m[rr][c] = R_C * g[rr][c] * (1.f - g[rr][c]);
        mv[c] = m[rr][c];
      }
      *(f32x4*)&buf[(r0 + rr) * LSTR5 + 4 + c0] = mv;
    }
    __syncthreads();

    f32x4 T4 = *(const f32x4*)&buf[rt * LSTR5 + 4 + c0];
    f32x4 B4 = *(const f32x4*)&buf[rb * LSTR5 + 4 + c0];
    float tl = buf[rt * LSTR5 + 3 + c0], tr = buf[rt * LSTR5 + 8 + c0];
    float bl = buf[rb * LSTR5 + 3 + c0], br = buf[rb * LSTR5 + 8 + c0];
    float sl0 = buf[r0 * LSTR5 + 3 + c0], sr0 = buf[r0 * LSTR5 + 8 + c0];
    float sl1 = buf[(r0 + 1) * LSTR5 + 3 + c0],
          sr1 = buf[(r0 + 1) * LSTR5 + 8 + c0];

    float rT[6], rA[6], rB6[6], rC[6];
    rT[0] = tl; rT[1] = T4[0]; rT[2] = T4[1]; rT[3] = T4[2]; rT[4] = T4[3];
    rT[5] = tr;
    rA[0] = sl0; rB6[0] = sl1;
#pragma unroll
    for (int c = 0; c < 4; c++) { rA[1 + c] = m[0][c]; rB6[1 + c] = m[1][c]; }
    rA[5] = sr0; rB6[5] = sr1;
    rC[0] = bl; rC[1] = B4[0]; rC[2] = B4[1]; rC[3] = B4[2]; rC[4] = B4[3];
    rC[5] = br;

    const int ulo = (s + 1 > img_lo) ? s + 1 : img_lo;
    const int uhi = (24 - s < img_hi) ? 24 - s : img_hi;

    if (r0 >= ulo && r0 <= uhi) {  // wave-uniform
#pragma unroll
      for (int c = 0; c < 4; c++) {
        float mc = rA[c + 1];
        float loc = k00 * rT[c] + k01 * rT[c + 1] + k02 * rT[c + 2] +
                    k10 * rA[c] + k11 * mc + k12 * rA[c + 2] +
                    k20 * rB6[c] + k21 * rB6[c + 1] + k22 * rB6[c + 2];
        float ph = (1.f - EPS_C) * mc + EPS_C * loc;
        float gn = (1.f - BETA_C) * ph + BETA_C * xv[0][c];
        g[0][c] = fminf(fmaxf(gn, CLAMP_LO), CLAMP_HI);
      }
    }
    if (r0 + 1 >= ulo && r0 + 1 <= uhi) {  // wave-uniform
#pragma unroll
      for (int c = 0; c < 4; c++) {
        float mc = rB6[c + 1];
        float loc = k00 * rA[c] + k01 * rA[c + 1] + k02 * rA[c + 2] +
                    k10 * rB6[c] + k11 * mc + k12 * rB6[c + 2] +
                    k20 * rC[c] + k21 * rC[c + 1] + k22 * rC[c + 2];
        float ph = (1.f - EPS_C) * mc + EPS_C * loc;
        float gn = (1.f - BETA_C) * ph + BETA_C * xv[1][c];
        g[1][c] = fminf(fmaxf(gn, CLAMP_LO), CLAMP_HI);
      }
    }
#pragma unroll
    for (int rr = 0; rr < 2; rr++) {
      int ry = r0 + rr;
      if (ry >= 5 && ry <= 20) {  // wave-uniform: tile rows accumulate
#pragma unroll
        for (int c = 0; c < 4; c++) {
          float gv = g[rr][c];
          float e = __expf((a1 * xv[rr][c] + a0c) * gv);
          se[rr][c] += e;
          ws[rr][c] = fmaf(e, gv, ws[rr][c]);
        }
      }
    }
  }

#pragma unroll
  for (int rr = 0; rr < 2; rr++) {
    int ry = r0 + rr;
    if (ry >= 5 && ry <= 20) {
      int gy = gy0 + ry;
      size_t gi = (size_t)b * NPIX + (size_t)gy * WW + c0;
      f32x4 gv;
#pragma unroll
      for (int c = 0; c < 4; c++) gv[c] = g[rr][c];
      *(f32x4*)&gOut[gi] = gv;
      if (last) {
        f32x4 sv;
#pragma unroll
        for (int c = 0; c < 4; c++) sv[c] = ws[rr][c] / se[rr][c];
        *(f32x4*)&sAout[gi] = sv;
      } else {
        f32x4 sev, wsv;
#pragma unroll
        for (int c = 0; c < 4; c++) { sev[c] = se[rr][c]; wsv[c] = ws[rr][c]; }
        *(f32x4*)&seB[gi] = sev;
        *(f32x4*)&wsB[gi] = wsv;
      }
    }
  }
}

// --------------------------- fallback single-launch stencil (R7, proven)
constexpr int BANDH = 16;
constexpr int LSTR2 = 264;
constexpr int TS = 768;

__global__ __launch_bounds__(TS) void stencil_kernel(
    const float* __restrict__ x, const float* __restrict__ Kl,
    const float* __restrict__ Wq, const float* __restrict__ bq,
    const float* __restrict__ Wk, float* __restrict__ lastO,
    float* __restrict__ sO) {
  __shared__ float buf[48 * LSTR2];

  const int band = blockIdx.x, b = blockIdx.y;
  const int gy0 = band * BANDH - 15;
  const int t = threadIdx.x;
  const int sx = t & 63, sy = t >> 6;
  const int c0 = 4 * sx, r0 = 4 * sy;
  const float* xim = x + (size_t)b * NPIX;

  if (t < 384) {
    int r = t >> 3, pw = t & 7;
    buf[r * LSTR2 + (pw < 4 ? pw : 256 + pw)] = 0.f;
  }

  const float k00 = Kl[0], k01 = Kl[1], k02 = Kl[2];
  const float k10 = Kl[3], k11 = Kl[4], k12 = Kl[5];
  const float k20 = Kl[6], k21 = Kl[7], k22 = Kl[8];

  const float swk = Wq[0] * Wk[0] + Wq[1] * Wk[1] + Wq[2] * Wk[2];
  const float sbk = bq[0] * Wk[0] + bq[1] * Wk[1] + bq[2] * Wk[2];
  const float rs3 = 0.57735026918962576f;
  const float a1 = swk * rs3, a0c = sbk * rs3;

  const int img_lo = (gy0 < 0) ? -gy0 : 0;
  const int img_hi = (255 - gy0 < 45) ? (255 - gy0) : 45;

  float xv[4][4], g[4][4], se[4][4], ws[4][4];
#pragma unroll
  for (int rr = 0; rr < 4; rr++) {
    int ry = r0 + rr, gy = gy0 + ry;
    bool rin = (ry >= img_lo) && (ry <= img_hi);
    f32x4 v = {0.f, 0.f, 0.f, 0.f};
    if (rin) v = *(const f32x4*)&xim[gy * WW + c0];
#pragma unroll
    for (int c = 0; c < 4; c++) {
      xv[rr][c] = v[c];
      g[rr][c] = v[c];
      se[rr][c] = 0.f;
      ws[rr][c] = 0.f;
    }
  }

  const int rt = (sy == 0) ? 0 : r0 - 1;
  const int rb = (sy == 11) ? 47 : r0 + 4;

  for (int s = 0; s < STEPS; s++) {
    if (s) __syncthreads();
    float m[4][4];
#pragma unroll
    for (int rr = 0; rr < 4; rr++) {
      f32x4 mv;
#pragma unroll
      for (int c = 0; c < 4; c++) {
        m[rr][c] = R_C * g[rr][c] * (1.f - g[rr][c]);
        mv[c] = m[rr][c];
      }
      *(f32x4*)&buf[(r0 + rr) * LSTR2 + 4 + c0] = mv;
    }
    __syncthreads();

    f32x4 T4 = *(const f32x4*)&buf[rt * LSTR2 + 4 + c0];
    float TL = buf[rt * LSTR2 + 3 + c0];
    float TR = buf[rt * LSTR2 + 8 + c0];
    f32x4 B4 = *(const f32x4*)&buf[rb * LSTR2 + 4 + c0];
    float BL = buf[rb * LSTR2 + 3 + c0];
    float BR = buf[rb * LSTR2 + 8 + c0];
    float sl[4], sr[4];
#pragma unroll
    for (int rr = 0; rr < 4; rr++) {
      sl[rr] = buf[(r0 + rr) * LSTR2 + 3 + c0];
      sr[rr] = buf[(r0 + rr) * LSTR2 + 8 + c0];
    }

    float W[6][6];
    W[0][0] = TL; W[0][1] = T4[0]; W[0][2] = T4[1];
    W[0][3] = T4[2]; W[0][4] = T4[3]; W[0][5] = TR;
#pragma unroll
    for (int rr = 0; rr < 4; rr++) {
      W[1 + rr][0] = sl[rr];
#pragma unroll
      for (int c = 0; c < 4; c++) W[1 + rr][1 + c] = m[rr][c];
      W[1 + rr][5] = sr[rr];
    }
    W[5][0] = BL; W[5][1] = B4[0]; W[5][2] = B4[1];
    W[5][3] = B4[2]; W[5][4] = B4[3]; W[5][5] = BR;

    const int ulo = (s + 1 > img_lo) ? s + 1 : img_lo;
    const int uhi = (44 - s < img_hi) ? 44 - s : img_hi;

#pragma unroll
    for (int rr = 0; rr < 4; rr++) {
      const int ry = r0 + rr;
      if (ry >= ulo && ry <= uhi) {
#pragma unroll
        for (int c = 0; c < 4; c++) {
          float mc = W[rr + 1][c + 1];
          float loc = k00 * W[rr][c] + k01 * W[rr][c + 1] +
                      k02 * W[rr][c + 2] + k10 * W[rr + 1][c] + k11 * mc +
                      k12 * W[rr + 1][c + 2] + k20 * W[rr + 2][c] +
                      k21 * W[rr + 2][c + 1] + k22 * W[rr + 2][c + 2];
          float ph = (1.f - EPS_C) * mc + EPS_C * loc;
          float gn = (1.f - BETA_C) * ph + BETA_C * xv[rr][c];
          g[rr][c] = fminf(fmaxf(gn, CLAMP_LO), CLAMP_HI);
        }
      }
      if (ry >= 15 && ry <= 30) {
#pragma unroll
        for (int c = 0; c < 4; c++) {
          float gv = g[rr][c];
          float e = __expf((a1 * xv[rr][c] + a0c) * gv);
          se[rr][c] += e;
          ws[rr][c] = fmaf(e, gv, ws[rr][c]);
        }
      }
    }
  }

#pragma unroll
  for (int rr = 0; rr < 4; rr++) {
    const int ry = r0 + rr;
    if (ry >= 15 && ry <= 30) {
      int gy = gy0 + ry;
      size_t gi = (size_t)b * NPIX + (size_t)gy * WW + c0;
      f32x4 gv, sv;
#pragma unroll
      for (int c = 0; c < 4; c++) {
        gv[c] = g[rr][c];
        sv[c] = ws[rr][c] / se[rr][c];
      }
      *(f32x4*)&lastO[gi] = gv;
      *(f32x4*)&sO[gi] = sv;
    }
  }
}

// ------------------------------------------------- conv stack via MFMA
constexpr int CT = 32;
constexpr int NR = 36, NCS = 37;
constexpr int T2 = 256;

__global__ __launch_bounds__(T2) void conv_kernel(
    const float* __restrict__ x, const float* __restrict__ lastA,
    const float* __restrict__ sA, const float* __restrict__ Wv,
    const float* __restrict__ bv, const unsigned short* __restrict__ apackG,
    const unsigned short* __restrict__ u1packG,
    const float* __restrict__ bfuG, const float* __restrict__ bu1G,
    const float* __restrict__ Wu2G, const float* __restrict__ bu2G,
    float* __restrict__ outp) {
  __shared__ __align__(16) unsigned short ncaL[NR * NCS * 8];
  __shared__ __align__(16) unsigned short featL[4 * 16 * 40];
  __shared__ __align__(16) float outL[CT * CT];

  const int cx0 = blockIdx.x * CT, cy0 = blockIdx.y * CT, b = blockIdx.z;
  const int t = threadIdx.x;
  const int w = t >> 6, lane = t & 63;
  const int g = lane >> 4, col = lane & 15;

  const float wv0 = Wv[0], wv1 = Wv[1], wv2 = Wv[2];
  const float bv0 = bv[0], bv1 = bv[1], bv2 = bv[2];
  for (int i = t; i < NR * NR; i += T2) {
    int ry = i / NR, rx = i - ry * NR;
    int gy = cy0 - 2 + ry, gx = cx0 - 2 + rx;
    unsigned short c[8];
    if (gy >= 0 && gy < HH && gx >= 0 && gx < WW) {
      size_t gi = (size_t)b * NPIX + (size_t)gy * WW + gx;
      float xvv = x[gi], lv = lastA[gi], sv = sA[gi];
      c[0] = f2bf(xvv);
      c[1] = f2bf(lv);
      c[2] = f2bf(lv - xvv);
      c[3] = f2bf(wv0 * sv + bv0);
      c[4] = f2bf(wv1 * sv + bv1);
      c[5] = f2bf(wv2 * sv + bv2);
    } else {
      c[0] = c[1] = c[2] = c[3] = c[4] = c[5] = 0;
    }
    short8 v;
    v[0] = (short)c[0]; v[1] = (short)c[1]; v[2] = (short)c[2];
    v[3] = (short)c[3]; v[4] = (short)c[4]; v[5] = (short)c[5];
    v[6] = 0; v[7] = 0;
    *(short8*)&ncaL[(ry * NCS + rx) * 8] = v;
  }

  const short8* ap = (const short8*)apackG;
  short8 wfr[10];
#pragma unroll
  for (int q = 0; q < 10; q++) wfr[q] = ap[q * 64 + lane];
  const short8* up = (const short8*)u1packG;
  short8 u1fr[2];
  u1fr[0] = up[lane];
  u1fr[1] = up[64 + lane];

  float bf0[4], bf1[4], bu1a[4], bu1b[4], wu2a[4], wu2b[4];
#pragma unroll
  for (int r = 0; r < 4; r++) {
    bf0[r] = bfuG[4 * g + r];
    bf1[r] = bfuG[16 + 4 * g + r];
    bu1a[r] = bu1G[4 * g + r];
    bu1b[r] = bu1G[16 + 4 * g + r];
    wu2a[r] = Wu2G[4 * g + r];
    wu2b[r] = Wu2G[16 + 4 * g + r];
  }
  const float bu2v = bu2G[0];

  int bofft[5];
#pragma unroll
  for (int tt = 0; tt < 5; tt++) {
    int vt = 4 * tt + g;
    bofft[tt] = VT_OY[vt] * NCS + VT_OX[vt];
  }

  __syncthreads();

  unsigned short* fw = &featL[w * 640];
  const f32x4 zacc = {0.f, 0.f, 0.f, 0.f};

  for (int rr = 0; rr < 8; rr++) {
    int py = 8 * w + rr;
#pragma unroll
    for (int half = 0; half < 2; half++) {
      int px0 = 16 * half;
      int cbase = py * NCS + px0 + col;
      f32x4 a0 = zacc, a1v = zacc;
#pragma unroll
      for (int tt = 0; tt < 5; tt++) {
        short8 bf = *(const short8*)&ncaL[(cbase + bofft[tt]) * 8];
        a0 = __builtin_amdgcn_mfma_f32_16x16x32_bf16(wfr[2 * tt], bf, a0, 0, 0, 0);
        a1v = __builtin_amdgcn_mfma_f32_16x16x32_bf16(wfr[2 * tt + 1], bf, a1v, 0, 0, 0);
      }
      unsigned p00, p01, p10, p11;
      {
        float f0 = fmaxf(a0[0] + bf0[0], 0.f), f1 = fmaxf(a0[1] + bf0[1], 0.f);
        float f2 = fmaxf(a0[2] + bf0[2], 0.f), f3 = fmaxf(a0[3] + bf0[3], 0.f);
        p00 = (unsigned)f2bf(f0) | ((unsigned)f2bf(f1) << 16);
        p01 = (unsigned)f2bf(f2) | ((unsigned)f2bf(f3) << 16);
        float h0 = fmaxf(a1v[0] + bf1[0], 0.f), h1 = fmaxf(a1v[1] + bf1[1], 0.f);
        float h2 = fmaxf(a1v[2] + bf1[2], 0.f), h3 = fmaxf(a1v[3] + bf1[3], 0.f);
        p10 = (unsigned)f2bf(h0) | ((unsigned)f2bf(h1) << 16);
        p11 = (unsigned)f2bf(h2) | ((unsigned)f2bf(h3) << 16);
      }
      uint2 wv_a; wv_a.x = p00; wv_a.y = p01;
      uint2 wv_b; wv_b.x = p10; wv_b.y = p11;
      *(uint2*)&fw[col * 40 + 4 * g] = wv_a;
      *(uint2*)&fw[col * 40 + 16 + 4 * g] = wv_b;
      short8 pf = *(const short8*)&fw[col * 40 + 8 * g];
      f32x4 hA = __builtin_amdgcn_mfma_f32_16x16x32_bf16(u1fr[0], pf, zacc, 0, 0, 0);
      f32x4 hB = __builtin_amdgcn_mfma_f32_16x16x32_bf16(u1fr[1], pf, zacc, 0, 0, 0);
      float cp = 0.f;
#pragma unroll
      for (int r = 0; r < 4; r++) {
        cp += wu2a[r] * fmaxf(hA[r] + bu1a[r], 0.f);
        cp += wu2b[r] * fmaxf(hB[r] + bu1b[r], 0.f);
      }
      cp += __shfl_xor(cp, 16);
      cp += __shfl_xor(cp, 32);
      float lastv = lastA[(size_t)b * NPIX + (size_t)(cy0 + py) * WW +
                          (cx0 + px0 + col)];
      float ov = fminf(fmaxf(lastv + bu2v + cp, 0.f), 1.f);
      if (lane < 16) outL[py * CT + px0 + col] = ov;
    }
  }

  float4 o4 = *(float4*)&outL[t * 4];
  int row = (t * 4) >> 5, colf = (t * 4) & 31;
  *(float4*)&outp[(size_t)b * NPIX + (size_t)(cy0 + row) * WW + cx0 + colf] = o4;
}

extern "C" void kernel_launch(void* const* d_in, const int* in_sizes, int n_in,
                              void* d_out, int out_size, void* d_ws,
                              size_t ws_size, hipStream_t stream) {
  const float* x = (const float*)d_in[0];
  const float* Kl = (const float*)d_in[1];
  const float* Wq = (const float*)d_in[2];
  const float* bq = (const float*)d_in[3];
  const float* Wk = (const float*)d_in[4];
  // d_in[5] = bk: softmax-invariant, unused
  const float* Wv = (const float*)d_in[6];
  const float* bv = (const float*)d_in[7];
  const float* Wp1 = (const float*)d_in[8];
  const float* bp1 = (const float*)d_in[9];
  const float* Wp2 = (const float*)d_in[10];
  const float* bp2 = (const float*)d_in[11];
  const float* alpha = (const float*)d_in[12];
  const float* Wu1 = (const float*)d_in[13];
  const float* bu1 = (const float*)d_in[14];
  const float* Wu2 = (const float*)d_in[15];
  const float* bu2 = (const float*)d_in[16];
  float* outp = (float*)d_out;

  const size_t BN = (size_t)BATCH * NPIX;
  float* ws = (float*)d_ws;
  const size_t packF = 5120 / 2 + 1024 / 2 + 64;  // pack area in floats
  const size_t need3 = (4 * BN + packF) * sizeof(float);

  const float *lastA, *sA;
  if (ws_size >= need3) {
    // 3-launch chained path: gB(->lastA), gC, seB(->sA), wsB
    float* gB = ws;
    float* gC = ws + BN;
    float* seB = ws + 2 * BN;
    float* wsB = ws + 3 * BN;
    unsigned short* apack = (unsigned short*)(ws + 4 * BN);
    unsigned short* u1pack = apack + 5120;
    float* bfu = (float*)(u1pack + 1024);

    prep_kernel<<<25, 256, 0, stream>>>(Wp1, Wp2, bp1, bp2, alpha, Wu1, apack,
                                        u1pack, bfu);
    dim3 g1(16, BATCH);
    stencil5_kernel<<<g1, T5, 0, stream>>>(x, Kl, Wq, bq, Wk, nullptr, gB,
                                           seB, wsB, nullptr, 1, 0);
    stencil5_kernel<<<g1, T5, 0, stream>>>(x, Kl, Wq, bq, Wk, gB, gC, seB,
                                           wsB, nullptr, 0, 0);
    stencil5_kernel<<<g1, T5, 0, stream>>>(x, Kl, Wq, bq, Wk, gC, gB, seB,
                                           wsB, seB, 0, 1);
    lastA = gB;
    sA = seB;  // last launch wrote ws/se into seB (per-thread RAW-safe)

    dim3 g2(WW / CT, HH / CT, BATCH);
    conv_kernel<<<g2, T2, 0, stream>>>(x, lastA, sA, Wv, bv, apack, u1pack,
                                       bfu, bu1, Wu2, bu2, outp);
  } else {
    // fallback: proven single-launch R7 path
    float* lastW = ws;
    float* sW = ws + BN;
    unsigned short* apack = (unsigned short*)(ws + 2 * BN);
    unsigned short* u1pack = apack + 5120;
    float* bfu = (float*)(u1pack + 1024);

    prep_kernel<<<25, 256, 0, stream>>>(Wp1, Wp2, bp1, bp2, alpha, Wu1, apack,
                                        u1pack, bfu);
    dim3 g1(HH / BANDH, BATCH);
    stencil_kernel<<<g1, TS, 0, stream>>>(x, Kl, Wq, bq, Wk, lastW, sW);
    dim3 g2(WW / CT, HH / CT, BATCH);
    conv_kernel<<<g2, T2, 0, stream>>>(x, lastW, sW, Wv, bv, apack, u1pack,
                                       bfu, bu1, Wu2, bu2, outp);
  }
}